// Round 12
// baseline (143.544 us; speedup 1.0000x reference)
//
#include <hip/hip_runtime.h>
#include <math.h>

// Problem constants (from reference):
constexpr int Bn = 1024;
constexpr int S  = 512;
constexpr int H  = 768;
constexpr int D1 = 128;
constexpr int HV = H / 4;     // 192 float4 per feature row

constexpr int NPOOL = Bn * 2;         // 2048 pool blocks
constexpr int NCLS  = 512;            // cls-head blocks
constexpr int NCRC  = 512;            // crc-head blocks
constexpr int NFIN  = Bn / 4;         // 256 finalize blocks

// ws layout:
//   flags: flag1[256], flag2[256] (uint) in first 4 KB (memset to 0 per call)
//   gp [2][Bn][768] floats — span-mean partials, pre-scaled by 1/len
//   P  [4][Bn][D1]  floats — per-chunk partial h dots

__device__ __forceinline__ void release_add(unsigned* f) {
  __hip_atomic_fetch_add(f, 1u, __ATOMIC_RELEASE, __HIP_MEMORY_SCOPE_AGENT);
}
__device__ __forceinline__ void acquire_spin(const unsigned* f, unsigned need) {
  while (__hip_atomic_load(f, __ATOMIC_ACQUIRE, __HIP_MEMORY_SCOPE_AGENT) < need) {
    __builtin_amdgcn_s_sleep(8);
  }
}

// Single launch, R8's block types pipelined via flags:
// [0,NPOOL): pool -> flag1[eg] (8/eg)
// [NPOOL,+NCLS): cls head (no wait) -> flag2[eg]
// [+NCRC): crc head, waits flag1[eg]==8 -> flag2[eg]
// [+NFIN): finalize, waits flag2[eg]==4 -> out
__global__ __launch_bounds__(256) void mega(
    const float* __restrict__ feat, const int* __restrict__ start,
    const int* __restrict__ endp, const float* __restrict__ W1,
    const float* __restrict__ b1, const float* __restrict__ W2,
    const float* __restrict__ b2, unsigned* __restrict__ flag1,
    unsigned* __restrict__ flag2, float* __restrict__ gp,
    float* __restrict__ P, float* __restrict__ out) {
  __shared__ float g[4][384];        // 6 KB (head paths)
  __shared__ float part[2][4][D1];   // 4 KB

  const int t = threadIdx.x;
  const unsigned bid = blockIdx.x;

  if (bid < NPOOL) {
    // ---- pool: R2/R8-exact span mean-pool ----
    const int b = bid >> 1;
    const int p = bid & 1;
    const int eg = b >> 2;
    if (t < 192) {
      const float4* base =
          reinterpret_cast<const float4*>(feat) + (size_t)b * (S * HV);
      const int s0 = start[b];
      const int s1 = endp[b];
      float4 a0{0,0,0,0}, a1{0,0,0,0}, a2{0,0,0,0}, a3{0,0,0,0};
      int s = s0 + p;
      for (; s + 6 < s1; s += 8) {
        float4 v0 = base[(size_t)(s    ) * HV + t];
        float4 v1 = base[(size_t)(s + 2) * HV + t];
        float4 v2 = base[(size_t)(s + 4) * HV + t];
        float4 v3 = base[(size_t)(s + 6) * HV + t];
        a0.x += v0.x; a0.y += v0.y; a0.z += v0.z; a0.w += v0.w;
        a1.x += v1.x; a1.y += v1.y; a1.z += v1.z; a1.w += v1.w;
        a2.x += v2.x; a2.y += v2.y; a2.z += v2.z; a2.w += v2.w;
        a3.x += v3.x; a3.y += v3.y; a3.z += v3.z; a3.w += v3.w;
      }
      for (; s < s1; s += 2) {
        float4 v = base[(size_t)s * HV + t];
        a0.x += v.x; a0.y += v.y; a0.z += v.z; a0.w += v.w;
      }
      const float inv = 1.0f / (float)(s1 - s0);
      float4 r;
      r.x = ((a0.x + a1.x) + (a2.x + a3.x)) * inv;
      r.y = ((a0.y + a1.y) + (a2.y + a3.y)) * inv;
      r.z = ((a0.z + a1.z) + (a2.z + a3.z)) * inv;
      r.w = ((a0.w + a1.w) + (a2.w + a3.w)) * inv;
      reinterpret_cast<float4*>(gp)[((size_t)p * Bn + b) * HV + t] = r;
    }
    __syncthreads();
    if (t == 0) release_add(&flag1[eg]);
    return;
  }

  if (bid < NPOOL + NCLS) {
    // ---- CLS-half head (R8-exact): chunk c in {0,1}, 4 examples ----
    const int hb = bid - NPOOL;
    const int c = hb & 1;
    const int eg = hb >> 1;
    const int e0 = eg * 4;
    const int dglob0 = c * 384;

    for (int i = t; i < 384; i += 256) {
      const int e = i / 96;
      const int j = i % 96;
      float4 v = *reinterpret_cast<const float4*>(
          feat + (size_t)(e0 + e) * S * H + dglob0 + j * 4);
      reinterpret_cast<float4*>(&g[e][0])[j] = v;
    }
    __syncthreads();

    const int k = t & (D1 - 1);
    const int sub = t >> 7;
    const int gofs = sub * 192;
    const float* Wc = W1 + (size_t)(dglob0 + gofs) * D1 + k;

    float a0 = 0.f, a1 = 0.f, a2 = 0.f, a3 = 0.f;
    #pragma unroll 4
    for (int d = 0; d < 192; d += 4) {
      float w0 = Wc[(size_t)(d + 0) * D1];
      float w1 = Wc[(size_t)(d + 1) * D1];
      float w2 = Wc[(size_t)(d + 2) * D1];
      float w3 = Wc[(size_t)(d + 3) * D1];
      float4 g0 = *reinterpret_cast<const float4*>(&g[0][gofs + d]);
      float4 g1 = *reinterpret_cast<const float4*>(&g[1][gofs + d]);
      float4 g2 = *reinterpret_cast<const float4*>(&g[2][gofs + d]);
      float4 g3 = *reinterpret_cast<const float4*>(&g[3][gofs + d]);
      a0 += g0.x * w0 + g0.y * w1 + g0.z * w2 + g0.w * w3;
      a1 += g1.x * w0 + g1.y * w1 + g1.z * w2 + g1.w * w3;
      a2 += g2.x * w0 + g2.y * w1 + g2.z * w2 + g2.w * w3;
      a3 += g3.x * w0 + g3.y * w1 + g3.z * w2 + g3.w * w3;
    }
    part[sub][0][k] = a0;
    part[sub][1][k] = a1;
    part[sub][2][k] = a2;
    part[sub][3][k] = a3;
    __syncthreads();

    if (t < D1) {
      #pragma unroll
      for (int e = 0; e < 4; ++e) {
        P[((size_t)c * Bn + (e0 + e)) * D1 + t] = part[0][e][t] + part[1][e][t];
      }
    }
    __syncthreads();
    if (t == 0) release_add(&flag2[eg]);
    return;
  }

  if (bid < NPOOL + NCLS + NCRC) {
    // ---- CRC-half head (R8-exact inner): chunk c in {2,3}, 4 examples ----
    const int hb = bid - (NPOOL + NCLS);
    const int c = 2 + (hb & 1);
    const int eg = hb >> 1;
    const int e0 = eg * 4;
    const int dglob0 = c * 384;
    const int dd0 = dglob0 - H;      // 0 or 384

    if (t == 0) acquire_spin(&flag1[eg], 8u);
    __syncthreads();

    for (int i = t; i < 384; i += 256) {
      const int e = i / 96;
      const int j = i % 96;
      const float* b0 = gp + (size_t)(e0 + e) * H + dd0;
      float4 u0 = reinterpret_cast<const float4*>(b0)[j];
      float4 u1 = reinterpret_cast<const float4*>(b0 + (size_t)Bn * H)[j];
      float4 v;
      v.x = u0.x + u1.x; v.y = u0.y + u1.y;
      v.z = u0.z + u1.z; v.w = u0.w + u1.w;
      reinterpret_cast<float4*>(&g[e][0])[j] = v;
    }
    __syncthreads();

    const int k = t & (D1 - 1);
    const int sub = t >> 7;
    const int gofs = sub * 192;
    const float* Wc = W1 + (size_t)(dglob0 + gofs) * D1 + k;

    float a0 = 0.f, a1 = 0.f, a2 = 0.f, a3 = 0.f;
    #pragma unroll 4
    for (int d = 0; d < 192; d += 4) {
      float w0 = Wc[(size_t)(d + 0) * D1];
      float w1 = Wc[(size_t)(d + 1) * D1];
      float w2 = Wc[(size_t)(d + 2) * D1];
      float w3 = Wc[(size_t)(d + 3) * D1];
      float4 g0 = *reinterpret_cast<const float4*>(&g[0][gofs + d]);
      float4 g1 = *reinterpret_cast<const float4*>(&g[1][gofs + d]);
      float4 g2 = *reinterpret_cast<const float4*>(&g[2][gofs + d]);
      float4 g3 = *reinterpret_cast<const float4*>(&g[3][gofs + d]);
      a0 += g0.x * w0 + g0.y * w1 + g0.z * w2 + g0.w * w3;
      a1 += g1.x * w0 + g1.y * w1 + g1.z * w2 + g1.w * w3;
      a2 += g2.x * w0 + g2.y * w1 + g2.z * w2 + g2.w * w3;
      a3 += g3.x * w0 + g3.y * w1 + g3.z * w2 + g3.w * w3;
    }
    part[sub][0][k] = a0;
    part[sub][1][k] = a1;
    part[sub][2][k] = a2;
    part[sub][3][k] = a3;
    __syncthreads();

    if (t < D1) {
      #pragma unroll
      for (int e = 0; e < 4; ++e) {
        P[((size_t)c * Bn + (e0 + e)) * D1 + t] = part[0][e][t] + part[1][e][t];
      }
    }
    __syncthreads();
    if (t == 0) release_add(&flag2[eg]);
    return;
  }

  // ---- finalize (R8-exact): 4 examples, waits for cls+crc partials ----
  {
    const int eg = bid - (NPOOL + NCLS + NCRC);
    const int e0 = eg * 4;
    if (t == 0) acquire_spin(&flag2[eg], 4u);
    __syncthreads();

    const int w = t >> 6, l = t & 63;
    const int e = e0 + w;
    const int k0 = l, k1 = l + 64;
    float h0 = b1[k0], h1 = b1[k1];
    #pragma unroll
    for (int c = 0; c < 4; ++c) {
      h0 += P[((size_t)c * Bn + e) * D1 + k0];
      h1 += P[((size_t)c * Bn + e) * D1 + k1];
    }
    h0 = fmaxf(h0, 0.f); h1 = fmaxf(h1, 0.f);
    float v = h0 * W2[k0] + h1 * W2[k1];
    #pragma unroll
    for (int off = 32; off > 0; off >>= 1) v += __shfl_down(v, off);
    if (l == 0) out[e] = 1.0f / (1.0f + expf(-(v + b2[0])));
  }
}

extern "C" void kernel_launch(void* const* d_in, const int* in_sizes, int n_in,
                              void* d_out, int out_size, void* d_ws, size_t ws_size,
                              hipStream_t stream) {
  const float* feat = (const float*)d_in[0];   // [B,S,H] fp32
  const int* start  = (const int*)d_in[1];     // [B]
  const int* endp   = (const int*)d_in[2];     // [B]
  const float* W1   = (const float*)d_in[3];   // [2H,D1]
  const float* b1   = (const float*)d_in[4];   // [D1]
  const float* W2   = (const float*)d_in[5];   // [D1,1]
  const float* b2   = (const float*)d_in[6];   // [1]
  float* out = (float*)d_out;                  // [B]

  unsigned* flag1 = (unsigned*)d_ws;                       // [256]
  unsigned* flag2 = flag1 + 256;                           // [256]
  float* gp = (float*)((char*)d_ws + 4096);                // [2][Bn][768]
  float* P  = gp + (size_t)2 * Bn * H;                     // [4][Bn][D1]

  hipMemsetAsync(d_ws, 0, 4096, stream);
  hipLaunchKernelGGL(mega, dim3(NPOOL + NCLS + NCRC + NFIN), dim3(256), 0,
                     stream, feat, start, endp, W1, b1, W2, b2,
                     flag1, flag2, gp, P, out);
}

// Round 13
// 37.993 us; speedup vs baseline: 3.7782x; 3.7782x over previous
//
#include <hip/hip_runtime.h>
#include <math.h>

// Problem constants (from reference):
constexpr int Bn = 1024;
constexpr int S  = 512;
constexpr int H  = 768;
constexpr int D1 = 128;
constexpr int HV = H / 4;     // 192 float4 per feature row
constexpr int NCLS = 512;     // CLS-half head blocks (R8-exact)

// ws layout (floats):
//   P    [2][Bn][D1] — CLS-half partial h dots (chunks 0,1)   (1 MB)
//   Pcrc [Bn][D1]    — CRC-half h dots (whole 768 rows)       (0.5 MB)

// Launch 1: grid = NCLS + Bn, 256 thr, all blocks co-resident (6/CU).
// [0,NCLS): R8-exact CLS-half head (reads feat row 0, writes P).
// [NCLS,+Bn): pool+crc — pool example b's span into an LDS mean, then
//             compute the full CRC-half W1 dot in-block (no cross-block dep).
__global__ __launch_bounds__(256, 6) void fused_launch1(
    const float* __restrict__ feat, const int* __restrict__ start,
    const int* __restrict__ endp, const float* __restrict__ W1,
    float* __restrict__ P, float* __restrict__ Pcrc) {
  __shared__ float g[4][384];        // 6 KB (cls path)
  __shared__ float part[2][4][D1];   // 4 KB (cls path)
  __shared__ float gcrc[H];          // 3 KB (pool+crc path)
  __shared__ float pcrc[2][D1];      // 1 KB (pool+crc path)

  const int t = threadIdx.x;
  const unsigned bid = blockIdx.x;

  if (bid < NCLS) {
    // ---- CLS-half head (R8-exact): chunk c in {0,1}, 4 examples ----
    const int c = bid & 1;
    const int e0 = (bid >> 1) * 4;
    const int dglob0 = c * 384;

    for (int i = t; i < 384; i += 256) {
      const int e = i / 96;          // 96 float4 per example-chunk
      const int j = i % 96;
      float4 v = *reinterpret_cast<const float4*>(
          feat + (size_t)(e0 + e) * S * H + dglob0 + j * 4);
      reinterpret_cast<float4*>(&g[e][0])[j] = v;
    }
    __syncthreads();

    const int k = t & (D1 - 1);
    const int sub = t >> 7;
    const int gofs = sub * 192;
    const float* Wc = W1 + (size_t)(dglob0 + gofs) * D1 + k;

    float a0 = 0.f, a1 = 0.f, a2 = 0.f, a3 = 0.f;
    #pragma unroll 4
    for (int d = 0; d < 192; d += 4) {
      float w0 = Wc[(size_t)(d + 0) * D1];
      float w1 = Wc[(size_t)(d + 1) * D1];
      float w2 = Wc[(size_t)(d + 2) * D1];
      float w3 = Wc[(size_t)(d + 3) * D1];
      float4 g0 = *reinterpret_cast<const float4*>(&g[0][gofs + d]);
      float4 g1 = *reinterpret_cast<const float4*>(&g[1][gofs + d]);
      float4 g2 = *reinterpret_cast<const float4*>(&g[2][gofs + d]);
      float4 g3 = *reinterpret_cast<const float4*>(&g[3][gofs + d]);
      a0 += g0.x * w0 + g0.y * w1 + g0.z * w2 + g0.w * w3;
      a1 += g1.x * w0 + g1.y * w1 + g1.z * w2 + g1.w * w3;
      a2 += g2.x * w0 + g2.y * w1 + g2.z * w2 + g2.w * w3;
      a3 += g3.x * w0 + g3.y * w1 + g3.z * w2 + g3.w * w3;
    }
    part[sub][0][k] = a0;
    part[sub][1][k] = a1;
    part[sub][2][k] = a2;
    part[sub][3][k] = a3;
    __syncthreads();

    if (t < D1) {
      #pragma unroll
      for (int e = 0; e < 4; ++e) {
        P[((size_t)c * Bn + (e0 + e)) * D1 + t] = part[0][e][t] + part[1][e][t];
      }
    }
    return;
  }

  // ---- pool + CRC-half head, one example per block ----
  const int b = bid - NCLS;
  if (t < 192) {
    const float4* base =
        reinterpret_cast<const float4*>(feat) + (size_t)b * (S * HV);
    const int s0 = start[b];
    const int s1 = endp[b];
    float4 a0{0,0,0,0}, a1{0,0,0,0}, a2{0,0,0,0}, a3{0,0,0,0};
    int s = s0;
    for (; s + 3 < s1; s += 4) {     // 4 independent loads in flight
      float4 v0 = base[(size_t)(s + 0) * HV + t];
      float4 v1 = base[(size_t)(s + 1) * HV + t];
      float4 v2 = base[(size_t)(s + 2) * HV + t];
      float4 v3 = base[(size_t)(s + 3) * HV + t];
      a0.x += v0.x; a0.y += v0.y; a0.z += v0.z; a0.w += v0.w;
      a1.x += v1.x; a1.y += v1.y; a1.z += v1.z; a1.w += v1.w;
      a2.x += v2.x; a2.y += v2.y; a2.z += v2.z; a2.w += v2.w;
      a3.x += v3.x; a3.y += v3.y; a3.z += v3.z; a3.w += v3.w;
    }
    for (; s < s1; ++s) {
      float4 v = base[(size_t)s * HV + t];
      a0.x += v.x; a0.y += v.y; a0.z += v.z; a0.w += v.w;
    }
    const float inv = 1.0f / (float)(s1 - s0);
    float4 r;
    r.x = ((a0.x + a1.x) + (a2.x + a3.x)) * inv;
    r.y = ((a0.y + a1.y) + (a2.y + a3.y)) * inv;
    r.z = ((a0.z + a1.z) + (a2.z + a3.z)) * inv;
    r.w = ((a0.w + a1.w) + (a2.w + a3.w)) * inv;
    reinterpret_cast<float4*>(gcrc)[t] = r;
  }
  __syncthreads();

  // CRC dot: thread = (k = t&127, sub = t>>7 -> 384-row half), 2 accumulators.
  {
    const int k = t & (D1 - 1);
    const int sub = t >> 7;
    const float* Wc = W1 + (size_t)(H + sub * 384) * D1 + k;
    const float* gb = gcrc + sub * 384;
    float accA = 0.f, accB = 0.f;
    #pragma unroll 4
    for (int j = 0; j < 384; j += 8) {
      float w0 = Wc[(size_t)(j + 0) * D1];
      float w1 = Wc[(size_t)(j + 1) * D1];
      float w2 = Wc[(size_t)(j + 2) * D1];
      float w3 = Wc[(size_t)(j + 3) * D1];
      float w4 = Wc[(size_t)(j + 4) * D1];
      float w5 = Wc[(size_t)(j + 5) * D1];
      float w6 = Wc[(size_t)(j + 6) * D1];
      float w7 = Wc[(size_t)(j + 7) * D1];
      float4 gA = *reinterpret_cast<const float4*>(gb + j);
      float4 gB = *reinterpret_cast<const float4*>(gb + j + 4);
      accA += gA.x * w0 + gA.y * w1 + gA.z * w2 + gA.w * w3;
      accB += gB.x * w4 + gB.y * w5 + gB.z * w6 + gB.w * w7;
    }
    pcrc[sub][k] = accA + accB;
  }
  __syncthreads();

  if (t < D1) {
    Pcrc[(size_t)b * D1 + t] = pcrc[0][t] + pcrc[1][t];
  }
}

// Launch 2: finalize. 4 examples/block; wave w owns example; lane l owns
// k-pair (l, l+64). h = b1 + Pcls0 + Pcls1 + Pcrc; relu; W2; sigmoid.
__global__ __launch_bounds__(256) void finalize(
    const float* __restrict__ P, const float* __restrict__ Pcrc,
    const float* __restrict__ b1, const float* __restrict__ W2,
    const float* __restrict__ b2, float* __restrict__ out) {
  const int t = threadIdx.x;
  const int w = t >> 6, l = t & 63;
  const int e = blockIdx.x * 4 + w;
  const int k0 = l, k1 = l + 64;
  float h0 = b1[k0] + P[((size_t)0 * Bn + e) * D1 + k0]
           + P[((size_t)1 * Bn + e) * D1 + k0] + Pcrc[(size_t)e * D1 + k0];
  float h1 = b1[k1] + P[((size_t)0 * Bn + e) * D1 + k1]
           + P[((size_t)1 * Bn + e) * D1 + k1] + Pcrc[(size_t)e * D1 + k1];
  h0 = fmaxf(h0, 0.f); h1 = fmaxf(h1, 0.f);
  float v = h0 * W2[k0] + h1 * W2[k1];
  #pragma unroll
  for (int off = 32; off > 0; off >>= 1) v += __shfl_down(v, off);
  if (l == 0) out[e] = 1.0f / (1.0f + expf(-(v + b2[0])));
}

extern "C" void kernel_launch(void* const* d_in, const int* in_sizes, int n_in,
                              void* d_out, int out_size, void* d_ws, size_t ws_size,
                              hipStream_t stream) {
  const float* feat = (const float*)d_in[0];   // [B,S,H] fp32
  const int* start  = (const int*)d_in[1];     // [B]
  const int* endp   = (const int*)d_in[2];     // [B]
  const float* W1   = (const float*)d_in[3];   // [2H,D1]
  const float* b1   = (const float*)d_in[4];   // [D1]
  const float* W2   = (const float*)d_in[5];   // [D1,1]
  const float* b2   = (const float*)d_in[6];   // [1]
  float* out = (float*)d_out;                  // [B]

  float* wsf  = (float*)d_ws;
  float* P    = wsf;                           // [2][Bn][D1]
  float* Pcrc = P + (size_t)2 * Bn * D1;       // [Bn][D1]

  hipLaunchKernelGGL(fused_launch1, dim3(NCLS + Bn), dim3(256), 0, stream,
                     feat, start, endp, W1, P, Pcrc);
  hipLaunchKernelGGL(finalize, dim3(Bn / 4), dim3(256), 0, stream,
                     P, Pcrc, b1, W2, b2, out);
}

// Round 14
// 33.958 us; speedup vs baseline: 4.2271x; 1.1188x over previous
//
#include <hip/hip_runtime.h>
#include <math.h>

// Problem constants (from reference):
constexpr int Bn = 1024;
constexpr int S  = 512;
constexpr int H  = 768;
constexpr int D1 = 128;
constexpr int HV = H / 4;     // 192 float4 per feature row
constexpr int NH = 512;       // cls-head blocks fused into launch 1

// ws layout (floats):
//   gp [2][Bn][768]  — span-mean partials (even/odd rows), pre-scaled by 1/len
//   P  [6][Bn][D1]   — partial h dots: [0,1]=CLS 384-chunks, [2..5]=CRC 192-chunks

// Launch 1 (R8-exact): blocks [0,NH) = CLS-half head; [NH,NH+2048) = pool.
__global__ __launch_bounds__(256) void fused_pool_clshead(
    const float* __restrict__ feat, const int* __restrict__ start,
    const int* __restrict__ endp, float* __restrict__ gp,
    const float* __restrict__ W1, float* __restrict__ P) {
  __shared__ float g[4][384];        // 6 KB (head path only)
  __shared__ float part[2][4][D1];   // 4 KB

  const int t = threadIdx.x;

  if (blockIdx.x < NH) {
    // ---- CLS-half head: chunk c in {0,1}, 4 examples ----
    const int c = blockIdx.x & 1;
    const int e0 = (blockIdx.x >> 1) * 4;
    const int dglob0 = c * 384;

    for (int i = t; i < 384; i += 256) {
      const int e = i / 96;          // 96 float4 per example-chunk
      const int j = i % 96;
      float4 v = *reinterpret_cast<const float4*>(
          feat + (size_t)(e0 + e) * S * H + dglob0 + j * 4);
      reinterpret_cast<float4*>(&g[e][0])[j] = v;
    }
    __syncthreads();

    const int k = t & (D1 - 1);
    const int sub = t >> 7;
    const int gofs = sub * 192;
    const float* Wc = W1 + (size_t)(dglob0 + gofs) * D1 + k;

    float a0 = 0.f, a1 = 0.f, a2 = 0.f, a3 = 0.f;
    #pragma unroll 4
    for (int d = 0; d < 192; d += 4) {
      float w0 = Wc[(size_t)(d + 0) * D1];
      float w1 = Wc[(size_t)(d + 1) * D1];
      float w2 = Wc[(size_t)(d + 2) * D1];
      float w3 = Wc[(size_t)(d + 3) * D1];
      float4 g0 = *reinterpret_cast<const float4*>(&g[0][gofs + d]);
      float4 g1 = *reinterpret_cast<const float4*>(&g[1][gofs + d]);
      float4 g2 = *reinterpret_cast<const float4*>(&g[2][gofs + d]);
      float4 g3 = *reinterpret_cast<const float4*>(&g[3][gofs + d]);
      a0 += g0.x * w0 + g0.y * w1 + g0.z * w2 + g0.w * w3;
      a1 += g1.x * w0 + g1.y * w1 + g1.z * w2 + g1.w * w3;
      a2 += g2.x * w0 + g2.y * w1 + g2.z * w2 + g2.w * w3;
      a3 += g3.x * w0 + g3.y * w1 + g3.z * w2 + g3.w * w3;
    }
    part[sub][0][k] = a0;
    part[sub][1][k] = a1;
    part[sub][2][k] = a2;
    part[sub][3][k] = a3;
    __syncthreads();

    if (t < D1) {
      #pragma unroll
      for (int e = 0; e < 4; ++e) {
        P[((size_t)c * Bn + (e0 + e)) * D1 + t] = part[0][e][t] + part[1][e][t];
      }
    }
    return;
  }

  // ---- pool: R2-exact span mean-pool ----
  if (t >= 192) return;              // wave 3 retires immediately
  const int bb = blockIdx.x - NH;
  const int b = bb >> 1;
  const int p = bb & 1;
  const float4* base = reinterpret_cast<const float4*>(feat) + (size_t)b * (S * HV);

  const int s0 = start[b];
  const int s1 = endp[b];
  float4 a0{0,0,0,0}, a1{0,0,0,0}, a2{0,0,0,0}, a3{0,0,0,0};
  int s = s0 + p;
  for (; s + 6 < s1; s += 8) {
    float4 v0 = base[(size_t)(s    ) * HV + t];
    float4 v1 = base[(size_t)(s + 2) * HV + t];
    float4 v2 = base[(size_t)(s + 4) * HV + t];
    float4 v3 = base[(size_t)(s + 6) * HV + t];
    a0.x += v0.x; a0.y += v0.y; a0.z += v0.z; a0.w += v0.w;
    a1.x += v1.x; a1.y += v1.y; a1.z += v1.z; a1.w += v1.w;
    a2.x += v2.x; a2.y += v2.y; a2.z += v2.z; a2.w += v2.w;
    a3.x += v3.x; a3.y += v3.y; a3.z += v3.z; a3.w += v3.w;
  }
  for (; s < s1; s += 2) {
    float4 v = base[(size_t)s * HV + t];
    a0.x += v.x; a0.y += v.y; a0.z += v.z; a0.w += v.w;
  }
  const float inv = 1.0f / (float)(s1 - s0);
  float4 r;
  r.x = ((a0.x + a1.x) + (a2.x + a3.x)) * inv;
  r.y = ((a0.y + a1.y) + (a2.y + a3.y)) * inv;
  r.z = ((a0.z + a1.z) + (a2.z + a3.z)) * inv;
  r.w = ((a0.w + a1.w) + (a2.w + a3.w)) * inv;
  reinterpret_cast<float4*>(gp)[((size_t)p * Bn + b) * HV + t] = r;
}

// Launch 2: CRC head, 4-way d-split for 2x concurrency vs R8.
// Block = 4 examples x 192-row CRC chunk cc in {0..3}; grid 1024 x 256 thr.
// Same W1 L2 traffic as R8 (100 MB), double the resident waves.
__global__ __launch_bounds__(256) void crc_head(
    const float* __restrict__ gp, const float* __restrict__ W1,
    float* __restrict__ P) {
  __shared__ float g[4][192];        // 3 KB: 4 examples' 192-row chunk
  __shared__ float part[2][4][D1];   // 4 KB

  const int t = threadIdx.x;
  const int cc = blockIdx.x & 3;     // CRC chunk 0..3
  const int e0 = (blockIdx.x >> 2) * 4;
  const int dd0 = cc * 192;          // offset within CRC half

  // Stage g: crc chunk = gp0 + gp1, 4 examples x 48 float4
  for (int i = t; i < 192; i += 256) {
    const int e = i / 48;
    const int j = i % 48;
    const float* b0 = gp + (size_t)(e0 + e) * H + dd0;
    float4 u0 = reinterpret_cast<const float4*>(b0)[j];
    float4 u1 = reinterpret_cast<const float4*>(b0 + (size_t)Bn * H)[j];
    float4 v;
    v.x = u0.x + u1.x; v.y = u0.y + u1.y;
    v.z = u0.z + u1.z; v.w = u0.w + u1.w;
    reinterpret_cast<float4*>(&g[e][0])[j] = v;
  }
  __syncthreads();

  const int k = t & (D1 - 1);
  const int sub = t >> 7;            // 96-row half of the chunk
  const int gofs = sub * 96;
  const float* Wc = W1 + (size_t)(H + dd0 + gofs) * D1 + k;

  float a0 = 0.f, a1 = 0.f, a2 = 0.f, a3 = 0.f;
  #pragma unroll 4
  for (int d = 0; d < 96; d += 4) {
    float w0 = Wc[(size_t)(d + 0) * D1];
    float w1 = Wc[(size_t)(d + 1) * D1];
    float w2 = Wc[(size_t)(d + 2) * D1];
    float w3 = Wc[(size_t)(d + 3) * D1];
    float4 g0 = *reinterpret_cast<const float4*>(&g[0][gofs + d]);
    float4 g1 = *reinterpret_cast<const float4*>(&g[1][gofs + d]);
    float4 g2 = *reinterpret_cast<const float4*>(&g[2][gofs + d]);
    float4 g3 = *reinterpret_cast<const float4*>(&g[3][gofs + d]);
    a0 += g0.x * w0 + g0.y * w1 + g0.z * w2 + g0.w * w3;
    a1 += g1.x * w0 + g1.y * w1 + g1.z * w2 + g1.w * w3;
    a2 += g2.x * w0 + g2.y * w1 + g2.z * w2 + g2.w * w3;
    a3 += g3.x * w0 + g3.y * w1 + g3.z * w2 + g3.w * w3;
  }
  part[sub][0][k] = a0;
  part[sub][1][k] = a1;
  part[sub][2][k] = a2;
  part[sub][3][k] = a3;
  __syncthreads();

  if (t < D1) {
    #pragma unroll
    for (int e = 0; e < 4; ++e) {
      P[((size_t)(2 + cc) * Bn + (e0 + e)) * D1 + t] =
          part[0][e][t] + part[1][e][t];
    }
  }
}

// Launch 3: combine 6 partial chunks, relu, dot W2, sigmoid. 1 wave/example.
__global__ __launch_bounds__(256) void finalize(
    const float* __restrict__ P, const float* __restrict__ b1,
    const float* __restrict__ W2, const float* __restrict__ b2,
    float* __restrict__ out) {
  const int t = threadIdx.x;
  const int w = t >> 6, l = t & 63;
  const int e = blockIdx.x * 4 + w;
  const int k0 = l, k1 = l + 64;
  float h0 = b1[k0], h1 = b1[k1];
  #pragma unroll
  for (int c = 0; c < 6; ++c) {
    h0 += P[((size_t)c * Bn + e) * D1 + k0];
    h1 += P[((size_t)c * Bn + e) * D1 + k1];
  }
  h0 = fmaxf(h0, 0.f); h1 = fmaxf(h1, 0.f);
  float v = h0 * W2[k0] + h1 * W2[k1];
  #pragma unroll
  for (int off = 32; off > 0; off >>= 1) v += __shfl_down(v, off);
  if (l == 0) out[e] = 1.0f / (1.0f + expf(-(v + b2[0])));
}

extern "C" void kernel_launch(void* const* d_in, const int* in_sizes, int n_in,
                              void* d_out, int out_size, void* d_ws, size_t ws_size,
                              hipStream_t stream) {
  const float* feat = (const float*)d_in[0];   // [B,S,H] fp32
  const int* start  = (const int*)d_in[1];     // [B]
  const int* endp   = (const int*)d_in[2];     // [B]
  const float* W1   = (const float*)d_in[3];   // [2H,D1]
  const float* b1   = (const float*)d_in[4];   // [D1]
  const float* W2   = (const float*)d_in[5];   // [D1,1]
  const float* b2   = (const float*)d_in[6];   // [1]
  float* out = (float*)d_out;                  // [B]

  float* wsf = (float*)d_ws;
  float* gp  = wsf;                            // [2][Bn][768]
  float* P   = gp + (size_t)2 * Bn * H;        // [6][Bn][D1]

  hipLaunchKernelGGL(fused_pool_clshead, dim3(NH + Bn * 2), dim3(256), 0,
                     stream, feat, start, endp, gp, W1, P);
  hipLaunchKernelGGL(crc_head, dim3(Bn), dim3(256), 0, stream, gp, W1, P);
  hipLaunchKernelGGL(finalize, dim3(Bn / 4), dim3(256), 0, stream,
                     P, b1, W2, b2, out);
}